// Round 1
// baseline (246.328 us; speedup 1.0000x reference)
//
#include <hip/hip_runtime.h>

typedef _Float16 f16;
typedef _Float16 f16x8 __attribute__((ext_vector_type(8)));
typedef float f32x4 __attribute__((ext_vector_type(4)));

#define MFMA16(a, b, c) __builtin_amdgcn_mfma_f32_16x16x32_f16((a), (b), (c), 0, 0, 0)

constexpr int SEQ   = 16;
constexpr int PLEN  = 15;
constexpr int BATCH = 32768;
constexpr int POSE  = 34;
constexpr int HD    = 64;
constexpr int NG    = 4 * HD;   // 256 gate rows
constexpr int WROW  = 136;      // K=128 padded +8 halfs (16B-aligned rows, breaks bank conflict)
constexpr int XROW  = 136;      // [h(0..63) | x(64..97) | zeros]
constexpr int FCROW = 72;       // K=64 padded +8
constexpr int FCR   = 48;       // fc rows padded 34 -> 48 (zero rows beyond 33)

constexpr int LDSH_W  = NG * WROW;       // 34816 halfs
constexpr int LDSH_XH = 4 * 32 * XROW;   // 17408 halfs
constexpr int LDSH_FC = FCR * FCROW;     // 3456 halfs
constexpr size_t SMEM_BYTES = (size_t)(LDSH_W + LDSH_XH + LDSH_FC) * 2;  // 111360 B

__device__ __forceinline__ float fsigm(float x) {
    // 1/(1+e^-x); e^-x -> inf => rcp(inf)=0, no NaN for finite x
    return __builtin_amdgcn_rcpf(1.0f + __expf(-x));
}
__device__ __forceinline__ float ftanh_(float x) {
    // 1 - 2/(e^{2x}+1); saturates cleanly to +-1
    return 1.0f - 2.0f * __builtin_amdgcn_rcpf(1.0f + __expf(2.0f * x));
}

__global__ __launch_bounds__(256, 1)
void lstm_fused(const float* __restrict__ obs,
                const float* __restrict__ Wih_e, const float* __restrict__ Whh_e,
                const float* __restrict__ b_e,
                const float* __restrict__ Wih_d, const float* __restrict__ Whh_d,
                const float* __restrict__ b_d,
                const float* __restrict__ fc_w, const float* __restrict__ fc_b,
                float* __restrict__ out)
{
    extern __shared__ f16 lds[];
    f16* Wl = lds;                     // [NG][WROW]  rows: [Whh(64) | Wih(34) | 0]
    f16* xh = lds + LDSH_W;            // [4][32][XROW] rows: [h(64) | x(34) | 0]
    f16* fl = lds + LDSH_W + LDSH_XH;  // [FCR][FCROW] rows p: [fc_w[p][0..63] | 0]

    const int tid  = threadIdx.x;
    const int lane = tid & 63;
    const int wv   = tid >> 6;         // wave 0..3
    const int l15  = lane & 15;
    const int l4   = lane >> 4;        // 0..3
    const int bbase = blockIdx.x * 128 + wv * 32;  // this wave's batch base

    f16* myxh = xh + wv * (32 * XROW);

    // ---- one-time init: zero xh (h0=0 + padding zeros), stage fc weights ----
    for (int i = tid; i < LDSH_XH; i += 256) xh[i] = (f16)0.0f;
    for (int i = tid; i < LDSH_FC; i += 256) {
        int r = i / FCROW, c = i - r * FCROW;
        float v = (r < POSE && c < HD) ? fc_w[r * HD + c] : 0.0f;
        fl[i] = (f16)v;
    }

    auto stageW = [&](const float* Wih, const float* Whh) {
        for (int i = tid; i < LDSH_W; i += 256) {
            int r = i / WROW, c = i - r * WROW;
            float v = 0.0f;
            if (c < HD)            v = Whh[r * HD + c];
            else if (c < HD + POSE) v = Wih[r * POSE + (c - HD)];
            Wl[i] = (f16)v;
        }
    };
    stageW(Wih_e, Whh_e);

    float bias[16];
    #pragma unroll
    for (int nf = 0; nf < 16; ++nf) bias[nf] = b_e[nf * 16 + l15];

    __syncthreads();

    // persistent cell state, C-fragment layout: [mf][n] x 4 rows; j = n*16 + l15
    f32x4 cst[2][4];
    #pragma unroll
    for (int mf = 0; mf < 2; ++mf) {
        #pragma unroll
        for (int n = 0; n < 4; ++n) cst[mf][n] = (f32x4)0.0f;
    }

    auto gates_update = [&]() {
        f32x4 acc[2][16];
        #pragma unroll
        for (int mf = 0; mf < 2; ++mf) {
            #pragma unroll
            for (int nf = 0; nf < 16; ++nf) acc[mf][nf] = (f32x4)bias[nf];
        }

        // A-frags: row = mf*16 + l15, k = kf*32 + l4*8 .. +7 (same mapping used for B)
        f16x8 a[2][4];
        #pragma unroll
        for (int mf = 0; mf < 2; ++mf) {
            #pragma unroll
            for (int kf = 0; kf < 4; ++kf)
                a[mf][kf] = *(const f16x8*)&myxh[(mf * 16 + l15) * XROW + kf * 32 + l4 * 8];
        }

        #pragma unroll
        for (int nf = 0; nf < 16; ++nf) {
            #pragma unroll
            for (int kf = 0; kf < 4; ++kf) {
                f16x8 b = *(const f16x8*)&Wl[(nf * 16 + l15) * WROW + kf * 32 + l4 * 8];
                acc[0][nf] = MFMA16(a[0][kf], b, acc[0][nf]);
                acc[1][nf] = MFMA16(a[1][kf], b, acc[1][nf]);
            }
        }

        // gate quadruple (i,f,g,o) = acc n, n+4, n+8, n+12 — same lane, same reg
        #pragma unroll
        for (int mf = 0; mf < 2; ++mf) {
            #pragma unroll
            for (int n = 0; n < 4; ++n) {
                #pragma unroll
                for (int r = 0; r < 4; ++r) {
                    float ig = acc[mf][n +  0][r];
                    float fg = acc[mf][n +  4][r];
                    float gg = acc[mf][n +  8][r];
                    float og = acc[mf][n + 12][r];
                    float cn = fsigm(fg) * cst[mf][n][r] + fsigm(ig) * ftanh_(gg);
                    float hn = fsigm(og) * ftanh_(cn);
                    cst[mf][n][r] = cn;
                    // write h back into A-layout rows (cols 0..63)
                    myxh[(mf * 16 + l4 * 4 + r) * XROW + (n * 16 + l15)] = (f16)hn;
                }
            }
        }
    };

    // ======== encoder: 16 steps ========
    #pragma unroll 1
    for (int t = 0; t < SEQ; ++t) {
        // stage x_t into cols 64..97 (coalesced: 1088 contiguous f32 per wave)
        const float* src = obs + ((size_t)t * BATCH + bbase) * POSE;
        #pragma unroll
        for (int i = 0; i < 17; ++i) {
            int idx = i * 64 + lane;        // 0..1087
            int row = idx / POSE;
            int p   = idx - row * POSE;
            myxh[row * XROW + HD + p] = (f16)src[idx];
        }
        __syncthreads();
        gates_update();
    }
    // note: x slot now holds obs_s[15] == decoder's first input. h,c carried in regs/LDS.

    // ======== switch to decoder weights ========
    __syncthreads();                 // all waves done reading enc Wl
    stageW(Wih_d, Whh_d);
    #pragma unroll
    for (int nf = 0; nf < 16; ++nf) bias[nf] = b_d[nf * 16 + l15];
    float fcb[3];
    #pragma unroll
    for (int nf = 0; nf < 3; ++nf) {
        int p = nf * 16 + l15;
        fcb[nf] = (p < POSE) ? fc_b[p] : 0.0f;
    }
    __syncthreads();

    // ======== decoder: 15 steps ========
    #pragma unroll 1
    for (int t = 0; t < PLEN; ++t) {
        gates_update();

        // curr = h_new @ fc_w^T + fc_b   (K=64 from cols 0..63, 16B-aligned)
        f32x4 acc3[2][3];
        #pragma unroll
        for (int mf = 0; mf < 2; ++mf) {
            #pragma unroll
            for (int nf = 0; nf < 3; ++nf) acc3[mf][nf] = (f32x4)fcb[nf];
        }
        f16x8 ah[2][2];
        #pragma unroll
        for (int mf = 0; mf < 2; ++mf) {
            #pragma unroll
            for (int kf = 0; kf < 2; ++kf)
                ah[mf][kf] = *(const f16x8*)&myxh[(mf * 16 + l15) * XROW + kf * 32 + l4 * 8];
        }
        #pragma unroll
        for (int nf = 0; nf < 3; ++nf) {
            #pragma unroll
            for (int kf = 0; kf < 2; ++kf) {
                f16x8 b = *(const f16x8*)&fl[(nf * 16 + l15) * FCROW + kf * 32 + l4 * 8];
                acc3[0][nf] = MFMA16(ah[0][kf], b, acc3[0][nf]);
                acc3[1][nf] = MFMA16(ah[1][kf], b, acc3[1][nf]);
            }
        }

        // store f32 output + feed back fp16 into x slot (cols 64..97)
        #pragma unroll
        for (int mf = 0; mf < 2; ++mf) {
            #pragma unroll
            for (int nf = 0; nf < 3; ++nf) {
                int p = nf * 16 + l15;
                if (p < POSE) {
                    #pragma unroll
                    for (int r = 0; r < 4; ++r) {
                        int row = mf * 16 + l4 * 4 + r;
                        float v = acc3[mf][nf][r];
                        out[((size_t)t * BATCH + bbase + row) * POSE + p] = v;
                        myxh[row * XROW + HD + p] = (f16)v;
                    }
                }
            }
        }
    }
}

extern "C" void kernel_launch(void* const* d_in, const int* in_sizes, int n_in,
                              void* d_out, int out_size, void* d_ws, size_t ws_size,
                              hipStream_t stream) {
    const float* obs   = (const float*)d_in[0];
    const float* Wih_e = (const float*)d_in[1];
    const float* Whh_e = (const float*)d_in[2];
    const float* b_e   = (const float*)d_in[3];
    const float* Wih_d = (const float*)d_in[4];
    const float* Whh_d = (const float*)d_in[5];
    const float* b_d   = (const float*)d_in[6];
    const float* fc_w  = (const float*)d_in[7];
    const float* fc_b  = (const float*)d_in[8];
    float* out = (float*)d_out;

    // 111 KB dynamic LDS (> default 64 KB) — request it every call (idempotent,
    // host-side attribute set, not a stream op, graph-capture safe)
    (void)hipFuncSetAttribute((const void*)lstm_fused,
                              hipFuncAttributeMaxDynamicSharedMemorySize,
                              (int)SMEM_BYTES);

    lstm_fused<<<dim3(BATCH / 128), dim3(256), SMEM_BYTES, stream>>>(
        obs, Wih_e, Whh_e, b_e, Wih_d, Whh_d, b_d, fc_w, fc_b, out);
}

// Round 3
// 240.251 us; speedup vs baseline: 1.0253x; 1.0253x over previous
//
#include <hip/hip_runtime.h>

typedef _Float16 f16;
typedef _Float16 f16x8 __attribute__((ext_vector_type(8)));
typedef float f32x4 __attribute__((ext_vector_type(4)));

#define MFMA16(a, b, c) __builtin_amdgcn_mfma_f32_16x16x32_f16((a), (b), (c), 0, 0, 0)

constexpr int SEQ   = 16;
constexpr int PLEN  = 15;
constexpr int BATCH = 32768;
constexpr int POSE  = 34;
constexpr int HD    = 64;
constexpr int XROW  = 136;              // row: [h 0..63 | x 64..97 | 1.0 @98 | 0 ..127 | pad]
constexpr int WH    = 256 * XROW;       // W' staging: 34816 halfs (69632 B)
constexpr int BUFH  = 2 * 2 * 32 * XROW;// dbuf x 2 groups x 32 rows: 17408 halfs (34816 B)
constexpr size_t SMEM = (size_t)(WH + BUFH) * 2;  // 104448 B

constexpr float LOG2E  = 1.4426950408889634f;
constexpr float LOG2E2 = 2.8853900817779268f;

__device__ __forceinline__ float rcpf(float x)  { return __builtin_amdgcn_rcpf(x); }
__device__ __forceinline__ float exp2f_(float x){ return __builtin_amdgcn_exp2f(x); }

__global__ __launch_bounds__(512, 2)
void lstm2(const float* __restrict__ obs,
           const float* __restrict__ Wih_e, const float* __restrict__ Whh_e,
           const float* __restrict__ b_e,
           const float* __restrict__ Wih_d, const float* __restrict__ Whh_d,
           const float* __restrict__ b_d,
           const float* __restrict__ fc_w, const float* __restrict__ fc_b,
           float* __restrict__ out)
{
    extern __shared__ f16 lds[];
    f16* Wt  = lds;        // [256][XROW] W' rows: [Whh | Wih | bias | 0], pre-scaled by log2e (2log2e for g-gate)
    f16* bfr = lds + WH;   // [buf][grp][row][XROW]

    const int tid  = threadIdx.x;
    const int lane = tid & 63;
    const int wv   = tid >> 6;     // 0..7
    const int g    = wv >> 2;      // row-group 0..1 (32 rows each)
    const int q    = wv & 3;       // gate-column split 0..3 (j = q*16 + l15)
    const int l15  = lane & 15;
    const int l4   = lane >> 4;
    const int blkbase = blockIdx.x * 64;

    auto stageW = [&](const float* Wih, const float* Whh, const float* b) {
        for (int i = tid; i < WH; i += 512) {
            int r = i / XROW, c = i - r * XROW;
            float sc = (r >= 128 && r < 192) ? LOG2E2 : LOG2E;  // g-gate rows get 2*log2e
            float v = 0.f;
            if (c < HD)        v = Whh[r * HD + c];
            else if (c < 98)   v = Wih[r * POSE + (c - HD)];
            else if (c == 98)  v = b[r];                         // bias column (A col 98 == 1.0)
            Wt[i] = (f16)(v * sc);
        }
    };

    f16x8 Bw[4][4];  // [gate i/f/g/o][kf] — step-invariant, register-resident
    auto loadB = [&]() {
        #pragma unroll
        for (int gg = 0; gg < 4; ++gg)
            #pragma unroll
            for (int kf = 0; kf < 4; ++kf)
                Bw[gg][kf] = *(const f16x8*)&Wt[((gg * 4 + q) * 16 + l15) * XROW + kf * 32 + l4 * 8];
    };

    auto stage_x = [&](int ts, int dstbuf) {
        const float* src = obs + ((size_t)ts * BATCH + blkbase) * POSE;  // 2176 contiguous f32
        #pragma unroll
        for (int it = 0; it < 5; ++it) {
            int i = it * 512 + tid;
            if (i < 64 * POSE) {
                int row = i / POSE, col = i - row * POSE;
                bfr[((dstbuf * 2 + (row >> 5)) * 32 + (row & 31)) * XROW + HD + col] = (f16)src[i];
            }
        }
    };

    // ---- init: zero buffers (+ constant-1 bias column), stage encoder W' ----
    for (int i = tid; i < BUFH; i += 512) {
        int c = i % XROW;
        bfr[i] = (c == 98) ? (f16)1.0f : (f16)0.0f;
    }
    stageW(Wih_e, Whh_e, b_e);
    __syncthreads();
    loadB();
    stage_x(0, 0);

    // fc weights straight from global into registers (one-time)
    const int p = q * 16 + l15;
    const bool fcw_ok = (q < 3) && (p < POSE);
    f16x8 Bfc[2];
    #pragma unroll
    for (int kf = 0; kf < 2; ++kf) {
        #pragma unroll
        for (int j = 0; j < 8; ++j) {
            float v = fcw_ok ? fc_w[p * HD + kf * 32 + l4 * 8 + j] : 0.f;
            Bfc[kf][j] = (f16)v;
        }
    }
    float fcb = fcw_ok ? fc_b[p] : 0.f;

    __syncthreads();

    f32x4 cst[2];  // cell state, rows mf*16 + l4*4 + r, col q*16+l15
    cst[0] = (f32x4)0.f;
    cst[1] = (f32x4)0.f;
    const f32x4 zz = (f32x4)0.f;

    int cur = 0;
    #pragma unroll 1
    for (int s = 0; s < SEQ + PLEN; ++s) {
        const int nxt = cur ^ 1;
        if (s == SEQ) {  // switch to decoder weights (bias col switches with them)
            stageW(Wih_d, Whh_d, b_d);
            __syncthreads();
            loadB();
        }
        const int rb = (cur * 2 + g) * 32;
        const int wb = (nxt * 2 + g) * 32;

        // A-frags: prev h + x from buf[cur]
        f16x8 a[2][4];
        #pragma unroll
        for (int mf = 0; mf < 2; ++mf)
            #pragma unroll
            for (int kf = 0; kf < 4; ++kf)
                a[mf][kf] = *(const f16x8*)&bfr[(rb + mf * 16 + l15) * XROW + kf * 32 + l4 * 8];

        // prefetch next x into buf[nxt] early — global latency hides under MFMA+nonlin
        if (s < SEQ) { int ts = (s + 1 < 15) ? s + 1 : 15; stage_x(ts, nxt); }

        // gates = [h|x|1] @ W'^T (bias via k=98 column; acc starts at zero)
        f32x4 acc[2][4];
        #pragma unroll
        for (int mf = 0; mf < 2; ++mf)
            #pragma unroll
            for (int gg = 0; gg < 4; ++gg) acc[mf][gg] = zz;
        #pragma unroll
        for (int kf = 0; kf < 4; ++kf) {
            #pragma unroll
            for (int gg = 0; gg < 4; ++gg) {
                acc[0][gg] = MFMA16(a[0][kf], Bw[gg][kf], acc[0][gg]);
                acc[1][gg] = MFMA16(a[1][kf], Bw[gg][kf], acc[1][gg]);
            }
        }

        // nonlinearity (gates pre-scaled by log2e; exp2 = 1 TRANS op) + h write to buf[nxt]
        #pragma unroll
        for (int mf = 0; mf < 2; ++mf) {
            #pragma unroll
            for (int r = 0; r < 4; ++r) {
                float si = rcpf(1.f + exp2f_(-acc[mf][0][r]));
                float sf = rcpf(1.f + exp2f_(-acc[mf][1][r]));
                float tg = 1.f - 2.f * rcpf(1.f + exp2f_(acc[mf][2][r]));   // g pre-scaled by 2log2e
                float so = rcpf(1.f + exp2f_(-acc[mf][3][r]));
                float c  = sf * cst[mf][r] + si * tg;
                float tc = 1.f - 2.f * rcpf(1.f + exp2f_(c * LOG2E2));
                float h  = so * tc;
                cst[mf][r] = c;
                bfr[(wb + mf * 16 + l4 * 4 + r) * XROW + q * 16 + l15] = (f16)h;
            }
        }

        if (s >= SEQ) {
            __syncthreads();  // all h of buf[nxt] complete -> fc reads full 64-wide h
            if (q < 3) {
                f16x8 ah[2][2];
                #pragma unroll
                for (int mf = 0; mf < 2; ++mf)
                    #pragma unroll
                    for (int kf = 0; kf < 2; ++kf)
                        ah[mf][kf] = *(const f16x8*)&bfr[(wb + mf * 16 + l15) * XROW + kf * 32 + l4 * 8];
                f32x4 o0 = {fcb, fcb, fcb, fcb}, o1 = {fcb, fcb, fcb, fcb};
                #pragma unroll
                for (int kf = 0; kf < 2; ++kf) {
                    o0 = MFMA16(ah[0][kf], Bfc[kf], o0);
                    o1 = MFMA16(ah[1][kf], Bfc[kf], o1);
                }
                if (p < POSE) {
                    float* ob = out + ((size_t)(s - SEQ) * BATCH + blkbase) * POSE;
                    #pragma unroll
                    for (int r = 0; r < 4; ++r) {
                        int r0 = l4 * 4 + r, r1 = 16 + l4 * 4 + r;
                        ob[(g * 32 + r0) * POSE + p] = o0[r];
                        ob[(g * 32 + r1) * POSE + p] = o1[r];
                        bfr[(wb + r0) * XROW + HD + p] = (f16)o0[r];   // fp16 feedback
                        bfr[(wb + r1) * XROW + HD + p] = (f16)o1[r];
                    }
                }
            }
        }
        __syncthreads();
        cur = nxt;
    }
}

extern "C" void kernel_launch(void* const* d_in, const int* in_sizes, int n_in,
                              void* d_out, int out_size, void* d_ws, size_t ws_size,
                              hipStream_t stream) {
    const float* obs   = (const float*)d_in[0];
    const float* Wih_e = (const float*)d_in[1];
    const float* Whh_e = (const float*)d_in[2];
    const float* b_e   = (const float*)d_in[3];
    const float* Wih_d = (const float*)d_in[4];
    const float* Whh_d = (const float*)d_in[5];
    const float* b_d   = (const float*)d_in[6];
    const float* fc_w  = (const float*)d_in[7];
    const float* fc_b  = (const float*)d_in[8];
    float* out = (float*)d_out;

    (void)hipFuncSetAttribute((const void*)lstm2,
                              hipFuncAttributeMaxDynamicSharedMemorySize,
                              (int)SMEM);

    lstm2<<<dim3(BATCH / 64), dim3(512), SMEM, stream>>>(
        obs, Wih_e, Whh_e, b_e, Wih_d, Whh_d, b_d, fc_w, fc_b, out);
}

// Round 4
// 223.212 us; speedup vs baseline: 1.1036x; 1.0763x over previous
//
#include <hip/hip_runtime.h>

typedef _Float16 f16;
typedef _Float16 f16x8 __attribute__((ext_vector_type(8)));
typedef float f32x4 __attribute__((ext_vector_type(4)));

#define MFMA16(a, b, c) __builtin_amdgcn_mfma_f32_16x16x32_f16((a), (b), (c), 0, 0, 0)

constexpr int SEQ   = 16;
constexpr int PLEN  = 15;
constexpr int BATCH = 32768;
constexpr int POSE  = 34;
constexpr int HD    = 64;
constexpr int ROWS  = 32;               // batch rows per block
constexpr int XROW  = 136;              // [h 0..63 | x 64..97 | 1.0 @98 | 0..127 | pad] (272B rows, 16B-aligned)

constexpr float LOG2E  = 1.4426950408889634f;
constexpr float LOG2E2 = 2.8853900817779268f;

__device__ __forceinline__ float rcpf(float x)   { return __builtin_amdgcn_rcpf(x); }
__device__ __forceinline__ float exp2f_(float x) { return __builtin_amdgcn_exp2f(x); }

__global__ __launch_bounds__(256, 4)
void lstm3(const float* __restrict__ obs,
           const float* __restrict__ Wih_e, const float* __restrict__ Whh_e,
           const float* __restrict__ b_e,
           const float* __restrict__ Wih_d, const float* __restrict__ Whh_d,
           const float* __restrict__ b_d,
           const float* __restrict__ fc_w, const float* __restrict__ fc_b,
           float* __restrict__ out)
{
    // LDS: ONLY the double-buffered [h|x|1] activation rows — 17408 B -> 4+ blocks/CU
    __shared__ f16 bfr[2 * ROWS * XROW];

    const int tid  = threadIdx.x;
    const int lane = tid & 63;
    const int q    = tid >> 6;     // wave 0..3 = gate-column split (j = q*16 + l15)
    const int l15  = lane & 15;
    const int l4   = lane >> 4;
    const int blkbase = blockIdx.x * ROWS;

    // ---- B-fragments built DIRECTLY from global (no LDS staging) ----
    // Bw[gg][kf] holds W'[(gg*4+q)*16+l15][kf*32+l4*8 .. +7], pre-scaled by log2e (2log2e for g)
    f16x8 Bw[4][4];
    auto loadB = [&](const float* __restrict__ Wih, const float* __restrict__ Whh,
                     const float* __restrict__ b) {
        #pragma unroll
        for (int gg = 0; gg < 4; ++gg) {
            const int r = (gg * 4 + q) * 16 + l15;     // gate row 0..255
            const float sc = (gg == 2) ? LOG2E2 : LOG2E;
            #pragma unroll
            for (int kf = 0; kf < 2; ++kf) {           // k 0..63 from Whh[r][.]
                const float* src = Whh + r * HD + kf * 32 + l4 * 8;
                #pragma unroll
                for (int j = 0; j < 8; ++j) Bw[gg][kf][j] = (f16)(src[j] * sc);
            }
            {                                          // k 64..95 from Wih[r][0..31]
                const float* src = Wih + r * POSE + l4 * 8;
                #pragma unroll
                for (int j = 0; j < 8; ++j) Bw[gg][2][j] = (f16)(src[j] * sc);
            }
            #pragma unroll
            for (int j = 0; j < 8; ++j) {              // k 96..127: Wih[32,33], bias@98, zeros
                const int k = 96 + l4 * 8 + j;
                float v = 0.f;
                if (k < 98)       v = Wih[r * POSE + (k - 64)];
                else if (k == 98) v = b[r];
                Bw[gg][3][j] = (f16)(v * sc);
            }
        }
    };
    loadB(Wih_e, Whh_e, b_e);

    auto stage_x = [&](int ts, int dstbuf) {
        const float* src = obs + ((size_t)ts * BATCH + blkbase) * POSE;  // 1088 contiguous f32
        #pragma unroll
        for (int it = 0; it < 5; ++it) {
            int i = it * 256 + tid;
            if (i < ROWS * POSE) {
                int row = i / POSE, col = i - row * POSE;
                bfr[(dstbuf * ROWS + row) * XROW + HD + col] = (f16)src[i];
            }
        }
    };

    // fc weights / bias straight into registers (one-time)
    const int p = q * 16 + l15;
    const bool fcw_ok = (q < 3) && (p < POSE);
    f16x8 Bfc[2];
    #pragma unroll
    for (int kf = 0; kf < 2; ++kf)
        #pragma unroll
        for (int j = 0; j < 8; ++j)
            Bfc[kf][j] = (f16)(fcw_ok ? fc_w[p * HD + kf * 32 + l4 * 8 + j] : 0.f);
    const float fcb = fcw_ok ? fc_b[p] : 0.f;

    // ---- init activation buffers: zeros (h0=0) + constant-1 bias column ----
    for (int i = tid; i < 2 * ROWS * XROW; i += 256) {
        int c = i % XROW;
        bfr[i] = (c == 98) ? (f16)1.0f : (f16)0.0f;
    }
    __syncthreads();
    stage_x(0, 0);
    __syncthreads();

    f32x4 cst[2];  // cell state: rows mf*16 + l4*4 + r, col q*16+l15
    cst[0] = (f32x4)0.f;
    cst[1] = (f32x4)0.f;
    const f32x4 zz = (f32x4)0.f;

    int cur = 0;
    #pragma unroll 1
    for (int s = 0; s < SEQ + PLEN; ++s) {
        const int nxt = cur ^ 1;
        if (s == SEQ) loadB(Wih_d, Whh_d, b_d);  // register-only weight switch, no barrier

        // A-frags: [h|x|1] rows from buf[cur]
        f16x8 a[2][4];
        #pragma unroll
        for (int mf = 0; mf < 2; ++mf)
            #pragma unroll
            for (int kf = 0; kf < 4; ++kf)
                a[mf][kf] = *(const f16x8*)&bfr[(cur * ROWS + mf * 16 + l15) * XROW + kf * 32 + l4 * 8];

        // prefetch next x into buf[nxt] (x-cols disjoint from h-cols; covered by step-end barrier)
        if (s < SEQ) { int ts = s + 1 < 15 ? s + 1 : 15; stage_x(ts, nxt); }

        // gates = [h|x|1] @ W'^T  (bias via k=98 column)
        f32x4 acc[2][4];
        #pragma unroll
        for (int mf = 0; mf < 2; ++mf)
            #pragma unroll
            for (int gg = 0; gg < 4; ++gg) acc[mf][gg] = zz;
        #pragma unroll
        for (int kf = 0; kf < 4; ++kf) {
            #pragma unroll
            for (int gg = 0; gg < 4; ++gg) {
                acc[0][gg] = MFMA16(a[0][kf], Bw[gg][kf], acc[0][gg]);
                acc[1][gg] = MFMA16(a[1][kf], Bw[gg][kf], acc[1][gg]);
            }
        }

        // nonlinearity (pre-scaled by log2e -> exp2) + h write to buf[nxt]
        #pragma unroll
        for (int mf = 0; mf < 2; ++mf) {
            #pragma unroll
            for (int r = 0; r < 4; ++r) {
                float si = rcpf(1.f + exp2f_(-acc[mf][0][r]));
                float sf = rcpf(1.f + exp2f_(-acc[mf][1][r]));
                float tg = 1.f - 2.f * rcpf(1.f + exp2f_(acc[mf][2][r]));   // g pre-scaled by 2log2e
                float so = rcpf(1.f + exp2f_(-acc[mf][3][r]));
                float c  = sf * cst[mf][r] + si * tg;
                float tc = 1.f - 2.f * rcpf(1.f + exp2f_(c * LOG2E2));
                cst[mf][r] = c;
                bfr[(nxt * ROWS + mf * 16 + l4 * 4 + r) * XROW + q * 16 + l15] = (f16)(so * tc);
            }
        }

        if (s >= SEQ) {
            __syncthreads();  // h complete -> fc reads full 64-wide h
            if (q < 3) {
                f16x8 ah[2][2];
                #pragma unroll
                for (int mf = 0; mf < 2; ++mf)
                    #pragma unroll
                    for (int kf = 0; kf < 2; ++kf)
                        ah[mf][kf] = *(const f16x8*)&bfr[(nxt * ROWS + mf * 16 + l15) * XROW + kf * 32 + l4 * 8];
                f32x4 o0 = {fcb, fcb, fcb, fcb}, o1 = {fcb, fcb, fcb, fcb};
                #pragma unroll
                for (int kf = 0; kf < 2; ++kf) {
                    o0 = MFMA16(ah[0][kf], Bfc[kf], o0);
                    o1 = MFMA16(ah[1][kf], Bfc[kf], o1);
                }
                if (p < POSE) {
                    float* ob = out + ((size_t)(s - SEQ) * BATCH + blkbase) * POSE;
                    #pragma unroll
                    for (int r = 0; r < 4; ++r) {
                        int r0 = l4 * 4 + r, r1 = 16 + l4 * 4 + r;
                        ob[r0 * POSE + p] = o0[r];
                        ob[r1 * POSE + p] = o1[r];
                        bfr[(nxt * ROWS + r0) * XROW + HD + p] = (f16)o0[r];   // fp16 feedback
                        bfr[(nxt * ROWS + r1) * XROW + HD + p] = (f16)o1[r];
                    }
                }
            }
        }
        __syncthreads();
        cur = nxt;
    }
}

extern "C" void kernel_launch(void* const* d_in, const int* in_sizes, int n_in,
                              void* d_out, int out_size, void* d_ws, size_t ws_size,
                              hipStream_t stream) {
    const float* obs   = (const float*)d_in[0];
    const float* Wih_e = (const float*)d_in[1];
    const float* Whh_e = (const float*)d_in[2];
    const float* b_e   = (const float*)d_in[3];
    const float* Wih_d = (const float*)d_in[4];
    const float* Whh_d = (const float*)d_in[5];
    const float* b_d   = (const float*)d_in[6];
    const float* fc_b_ = (const float*)d_in[8];
    const float* fc_w  = (const float*)d_in[7];
    float* out = (float*)d_out;

    lstm3<<<dim3(BATCH / ROWS), dim3(256), 0, stream>>>(
        obs, Wih_e, Whh_e, b_e, Wih_d, Whh_d, b_d, fc_w, fc_b_, out);
}